// Round 2
// baseline (537.493 us; speedup 1.0000x reference)
//
#include <hip/hip_runtime.h>
#include <hip/hip_bf16.h>

// Problem constants
#define B_   2
#define S_   2048
#define HD_  2048
#define H_   4
#define DK_  256
#define DV_  512
#define KD_  1024   // H_*DK_
#define VD_  2048   // H_*DV_
#define ND_  6144   // fused N: q(1024) | k(1024) | v(2048) | g(2048)
#define M_   4096   // B_*S_
#define NCHUNK_ 32
#define CHUNK_  64

typedef __attribute__((ext_vector_type(8))) short bf16x8;
typedef __attribute__((ext_vector_type(4))) float f32x4;
typedef __attribute__((ext_vector_type(4))) unsigned short us4;
typedef __attribute__((ext_vector_type(8))) unsigned short us8;

__device__ __forceinline__ unsigned short f2bf(float f) {
    __hip_bfloat16 h = __float2bfloat16(f);
    return *reinterpret_cast<unsigned short*>(&h);
}
__device__ __forceinline__ float bf2f(unsigned short u) {
    unsigned int x = ((unsigned int)u) << 16;
    return *reinterpret_cast<float*>(&x);
}

// Direct global->LDS DMA, 16B per lane. LDS dest must be wave-uniform base;
// HW writes base + lane*16. All our staging layouts are lane-linear (byte
// offset == tid*16), so base = &buf[wave*512] (shorts).
typedef const __attribute__((address_space(1))) unsigned int* gas_ptr;
typedef __attribute__((address_space(3))) unsigned int* las_ptr;
__device__ __forceinline__ void gload16(const void* g, void* l) {
    __builtin_amdgcn_global_load_lds((gas_ptr)g, (las_ptr)l, 16, 0, 0);
}

// ---------------------------------------------------------------------------
// fp32 -> bf16 flat convert (x). One float4 per thread.
// ---------------------------------------------------------------------------
__global__ __launch_bounds__(256) void conv_bf16(const float* __restrict__ in,
                                                 unsigned short* __restrict__ out) {
    const int idx = blockIdx.x * 256 + threadIdx.x;
    float4 a = *(const float4*)&in[(size_t)idx * 4];
    us4 w; w.x = f2bf(a.x); w.y = f2bf(a.y); w.z = f2bf(a.z); w.w = f2bf(a.w);
    *(us4*)&out[(size_t)idx * 4] = w;
}

// ---------------------------------------------------------------------------
// Weight transpose: Wt[n][k](bf16) = W[k][n](fp32). 32x32 tiles via LDS.
// ---------------------------------------------------------------------------
__global__ __launch_bounds__(256) void tr_w(const float* __restrict__ W,
                                            unsigned short* __restrict__ Wt,
                                            int K, int N) {
    __shared__ float Ws[32][33];
    const int t = threadIdx.x;
    const int n0 = blockIdx.x * 32, k0 = blockIdx.y * 32;
    const int r = t >> 3, c4 = (t & 7) * 4;
    float4 a = *(const float4*)&W[(size_t)(k0 + r) * N + n0 + c4];
    Ws[r][c4 + 0] = a.x; Ws[r][c4 + 1] = a.y; Ws[r][c4 + 2] = a.z; Ws[r][c4 + 3] = a.w;
    __syncthreads();
    const int nr = t >> 3, kc4 = (t & 7) * 4;
    us4 w;
#pragma unroll
    for (int j = 0; j < 4; ++j) w[j] = f2bf(Ws[kc4 + j][nr]);
    *(us4*)&Wt[(size_t)(n0 + nr) * K + k0 + kc4] = w;
}

// ---------------------------------------------------------------------------
// v transpose: vT[((b*H+h)*512+e)*2048 + s] = qkvg[(b*2048+s)*6144 + 2048 + h*512 + e]
// bf16 in/out, 32x32 tiles. grid(x = 64 e-tiles, y = 128 s-tiles).
// ---------------------------------------------------------------------------
__global__ __launch_bounds__(256) void tr_v(const unsigned short* __restrict__ qkvg,
                                            unsigned short* __restrict__ vT) {
    __shared__ unsigned short Ws[32][36];
    const int t = threadIdx.x;
    const int c0 = blockIdx.x * 32;      // v-col within VD (0..2047)
    const int s0 = blockIdx.y * 32;      // global s (0..4095)
    {
        const int r = t >> 3, c4 = (t & 7) * 4;
        us4 w = *(const us4*)&qkvg[(size_t)(s0 + r) * ND_ + 2048 + c0 + c4];
        *(us4*)&Ws[r][c4] = w;
    }
    __syncthreads();
    const int er = t >> 3, sc4 = (t & 7) * 4;
    const int c = c0 + er;
    const int h = c >> 9, e = c & 511;
    const int b = s0 >> 11, srow = s0 & 2047;
    us4 w;
#pragma unroll
    for (int j = 0; j < 4; ++j) w[j] = Ws[sc4 + j][er];
    *(us4*)&vT[((size_t)(b * H_ + h) * 512 + e) * 2048 + srow + sc4] = w;
}

// ---------------------------------------------------------------------------
// bf16 GEMM: C[M][N] = A[M][K] @ Bt[N][K]^T. A,Bt bf16 row-major (K-contig).
// 128x128 tile, BK=32, global_load_lds width=16 staging (m97 structure).
// Lane-linear unpadded [row*32] LDS, conflict-free.
// ---------------------------------------------------------------------------
__global__ __launch_bounds__(256) void gemm_bt(const unsigned short* __restrict__ A,
                                               const unsigned short* __restrict__ Bt,
                                               float* __restrict__ Cf,
                                               unsigned short* __restrict__ Cb,
                                               int M, int N, int K) {
    __shared__ __align__(16) unsigned short As[128 * 32];
    __shared__ __align__(16) unsigned short Bs[128 * 32];
    const int t = threadIdx.x;
    const int m0 = blockIdx.y * 128, n0 = blockIdx.x * 128;
    const int wave = t >> 6, lane = t & 63;
    const int quad = lane >> 4, l16 = lane & 15;
    const int wm = (wave >> 1) * 64, wn = (wave & 1) * 64;
    const int srow = t >> 2, scol = (t & 3) * 8;

    f32x4 acc[4][4] = {};

    const unsigned short* Ar0 = &A[(size_t)(m0 + srow) * K + scol];
    const unsigned short* Ar1 = &A[(size_t)(m0 + srow + 64) * K + scol];
    const unsigned short* Br0 = &Bt[(size_t)(n0 + srow) * K + scol];
    const unsigned short* Br1 = &Bt[(size_t)(n0 + srow + 64) * K + scol];
    unsigned short* lA0 = &As[wave * 512];
    unsigned short* lA1 = &As[2048 + wave * 512];
    unsigned short* lB0 = &Bs[wave * 512];
    unsigned short* lB1 = &Bs[2048 + wave * 512];

    for (int k0 = 0; k0 < K; k0 += 32) {
        __syncthreads();
        gload16(Ar0 + k0, lA0);
        gload16(Ar1 + k0, lA1);
        gload16(Br0 + k0, lB0);
        gload16(Br1 + k0, lB1);
        __syncthreads();

        bf16x8 af[4], bfr[4];
#pragma unroll
        for (int i = 0; i < 4; ++i)
            af[i] = *(const bf16x8*)&As[(wm + i * 16 + l16) * 32 + quad * 8];
#pragma unroll
        for (int j = 0; j < 4; ++j)
            bfr[j] = *(const bf16x8*)&Bs[(wn + j * 16 + l16) * 32 + quad * 8];
#pragma unroll
        for (int i = 0; i < 4; ++i)
#pragma unroll
            for (int j = 0; j < 4; ++j)
                acc[i][j] = __builtin_amdgcn_mfma_f32_16x16x32_bf16(af[i], bfr[j], acc[i][j], 0, 0, 0);
    }

    if (Cb) {
#pragma unroll
        for (int i = 0; i < 4; ++i)
#pragma unroll
            for (int j = 0; j < 4; ++j)
#pragma unroll
                for (int r = 0; r < 4; ++r)
                    Cb[(size_t)(m0 + wm + i * 16 + quad * 4 + r) * N + n0 + wn + j * 16 + l16] = f2bf(acc[i][j][r]);
    } else {
#pragma unroll
        for (int i = 0; i < 4; ++i)
#pragma unroll
            for (int j = 0; j < 4; ++j)
#pragma unroll
                for (int r = 0; r < 4; ++r)
                    Cf[(size_t)(m0 + wm + i * 16 + quad * 4 + r) * N + n0 + wn + j * 16 + l16] = acc[i][j][r];
    }
}

// ---------------------------------------------------------------------------
// T = X @ Wgk1 (fp32, K=2048, N=16), LDS-staged.
// ---------------------------------------------------------------------------
__global__ __launch_bounds__(256) void gemm_n16(const float* __restrict__ X,
                                                const float* __restrict__ W,
                                                float* __restrict__ T) {
    __shared__ float Xs[16][129];
    __shared__ float Wsh[128][17];
    const int t = threadIdx.x;
    const int m0 = blockIdx.x * 16;
    const int mm = t >> 4, jj = t & 15;
    float acc = 0.f;
    for (int k0 = 0; k0 < HD_; k0 += 128) {
        __syncthreads();
#pragma unroll
        for (int p = 0; p < 2; ++p) {
            int q = t + p * 256;
            int r = q >> 5, c4 = (q & 31) * 4;
            float4 a = *(const float4*)&X[(size_t)(m0 + r) * HD_ + k0 + c4];
            Xs[r][c4 + 0] = a.x; Xs[r][c4 + 1] = a.y; Xs[r][c4 + 2] = a.z; Xs[r][c4 + 3] = a.w;
        }
#pragma unroll
        for (int p = 0; p < 8; ++p) {
            int q = t + p * 256;
            int r = q >> 4, c = q & 15;
            Wsh[r][c] = W[(size_t)(k0 + r) * 16 + c];
        }
        __syncthreads();
#pragma unroll 16
        for (int kk = 0; kk < 128; ++kk) acc += Xs[mm][kk] * Wsh[kk][jj];
    }
    T[(size_t)(m0 + mm) * 16 + jj] = acc;
}

// ---------------------------------------------------------------------------
// gk = log_sigmoid(T @ Wgk2 + bgk2) / 16.
// ---------------------------------------------------------------------------
__global__ __launch_bounds__(256) void gk_act(const float* __restrict__ T,
                                              const float* __restrict__ W2,
                                              const float* __restrict__ b2,
                                              float* __restrict__ gk) {
    const int idx = blockIdx.x * 256 + threadIdx.x;
    const int n = idx & 1023;
    const int m = idx >> 10;
    float acc = b2[n];
#pragma unroll
    for (int j = 0; j < 16; ++j) acc += T[m * 16 + j] * W2[j * 1024 + n];
    float ls = (acc < 0.f) ? (acc - log1pf(expf(acc))) : (-log1pf(expf(-acc)));
    gk[idx] = ls * 0.0625f;  // / GATE_NORMALIZER
}

// ---------------------------------------------------------------------------
// Gate prep: reads q,k columns of fused qkvg (stride ND_); writes
// qg,kg (compact t-major), kgT (d-major: [bh*256+d][s]), gle.
// ---------------------------------------------------------------------------
__global__ __launch_bounds__(256) void gate_prep(const unsigned short* __restrict__ qkvg,
                                                 const float* __restrict__ gk,
                                                 unsigned short* __restrict__ qg,
                                                 unsigned short* __restrict__ kg,
                                                 unsigned short* __restrict__ kgT,
                                                 float* __restrict__ glexp) {
    const int idx = blockIdx.x * 256 + threadIdx.x;
    const int d = idx & 255;
    const int chunk = (idx >> 8) & 31;
    const int h = (idx >> 13) & 3;
    const int b = idx >> 15;
    const int bh = b * H_ + h;
    const size_t col = h * 256 + d;
    const size_t rowbase = (size_t)b * S_ + chunk * 64;
    const size_t kgT_base = ((size_t)bh * 256 + d) * 2048 + chunk * 64;
    const float scale = 0.0625f;  // DK^-0.5
    float gc = 0.f;
    for (int t = 0; t < 64; ++t) {
        size_t r = rowbase + t;
        gc += gk[r * (size_t)KD_ + col];
        unsigned short qv = qkvg[r * (size_t)ND_ + col];
        unsigned short kv = qkvg[r * (size_t)ND_ + 1024 + col];
        unsigned short kgv = f2bf(bf2f(kv) * expf(-gc));
        qg[r * (size_t)KD_ + col] = f2bf(bf2f(qv) * expf(gc) * scale);
        kg[r * (size_t)KD_ + col] = kgv;
        kgT[kgT_base + t] = kgv;
    }
    glexp[idx] = expf(gc);
}

// ---------------------------------------------------------------------------
// Pass C1: A_s[bhc][t][j] = tril(q_g k_g^T) (64x64, K=256) -> bf16.
// global_load_lds staging.
// ---------------------------------------------------------------------------
__global__ __launch_bounds__(256) void pass_c1(const unsigned short* __restrict__ qg,
                                               const unsigned short* __restrict__ kg,
                                               unsigned short* __restrict__ Asg) {
    __shared__ __align__(16) unsigned short Aq[64 * 32];
    __shared__ __align__(16) unsigned short Bk[64 * 32];
    const int t = threadIdx.x;
    const int bhc = blockIdx.x;
    const int chunk = bhc & 31, bh = bhc >> 5;
    const int h = bh & 3, b = bh >> 2;
    const int s0 = chunk * 64;
    const int wave = t >> 6, lane = t & 63;
    const int quad = lane >> 4, l16 = lane & 15;
    const int srow = t >> 2, scol = (t & 3) * 8;
    const size_t base = (size_t)b * S_ * KD_ + h * DK_ + (size_t)(s0 + srow) * KD_ + scol;

    f32x4 acc[4] = {};
    unsigned short* lA = &Aq[wave * 512];
    unsigned short* lB = &Bk[wave * 512];

    for (int k0 = 0; k0 < 256; k0 += 32) {
        __syncthreads();
        gload16(&qg[base + k0], lA);
        gload16(&kg[base + k0], lB);
        __syncthreads();
        bf16x8 bfr = *(const bf16x8*)&Bk[(wave * 16 + l16) * 32 + quad * 8];
#pragma unroll
        for (int i = 0; i < 4; ++i) {
            bf16x8 af = *(const bf16x8*)&Aq[(i * 16 + l16) * 32 + quad * 8];
            acc[i] = __builtin_amdgcn_mfma_f32_16x16x32_bf16(af, bfr, acc[i], 0, 0, 0);
        }
    }

    const int j = wave * 16 + l16;
#pragma unroll
    for (int i = 0; i < 4; ++i)
#pragma unroll
        for (int r = 0; r < 4; ++r) {
            int m = i * 16 + quad * 4 + r;
            float val = (j <= m) ? acc[i][r] : 0.f;
            Asg[(size_t)bhc * 4096 + m * 64 + j] = f2bf(val);
        }
}

// ---------------------------------------------------------------------------
// Pass A: Dt[bhc][e][d] = sum_t v[t,e]*k_g[t,d]. A-rows from vT, B-rows from
// kgT — both contiguous, global_load_lds staging. grid(2,4,256).
// ---------------------------------------------------------------------------
__global__ __launch_bounds__(256) void pass_a(const unsigned short* __restrict__ kgT,
                                              const unsigned short* __restrict__ vT,
                                              unsigned short* __restrict__ Dt) {
    __shared__ __align__(16) unsigned short As[128 * 32];  // [e][t]
    __shared__ __align__(16) unsigned short Bs[128 * 32];  // [d][t]
    const int t = threadIdx.x;
    const int bhc = blockIdx.z;
    const int chunk = bhc & 31, bh = bhc >> 5;
    const int s0 = chunk * 64;
    const int e0 = blockIdx.y * 128;
    const int d0 = blockIdx.x * 128;
    const int wave = t >> 6, lane = t & 63;
    const int quad = lane >> 4, l16 = lane & 15;
    const int wm = (wave >> 1) * 64, wn = (wave & 1) * 64;

    f32x4 acc[4][4] = {};

    for (int k0 = 0; k0 < 64; k0 += 32) {
        __syncthreads();
#pragma unroll
        for (int p = 0; p < 2; ++p) {
            int q = t + p * 256;
            int row = q >> 2, c8 = (q & 3) * 8;
            gload16(&vT[((size_t)bh * 512 + e0 + row) * 2048 + s0 + k0 + c8],
                    &As[p * 2048 + wave * 512]);
            gload16(&kgT[((size_t)bh * 256 + d0 + row) * 2048 + s0 + k0 + c8],
                    &Bs[p * 2048 + wave * 512]);
        }
        __syncthreads();

        bf16x8 af[4], bfr[4];
#pragma unroll
        for (int i = 0; i < 4; ++i)
            af[i] = *(const bf16x8*)&As[(wm + i * 16 + l16) * 32 + quad * 8];
#pragma unroll
        for (int j = 0; j < 4; ++j)
            bfr[j] = *(const bf16x8*)&Bs[(wn + j * 16 + l16) * 32 + quad * 8];
#pragma unroll
        for (int i = 0; i < 4; ++i)
#pragma unroll
            for (int j = 0; j < 4; ++j)
                acc[i][j] = __builtin_amdgcn_mfma_f32_16x16x32_bf16(af[i], bfr[j], acc[i][j], 0, 0, 0);
    }

#pragma unroll
    for (int i = 0; i < 4; ++i)
#pragma unroll
        for (int j = 0; j < 4; ++j)
#pragma unroll
            for (int r = 0; r < 4; ++r) {
                size_t e = e0 + wm + i * 16 + quad * 4 + r;
                size_t d = d0 + wn + j * 16 + l16;
                Dt[((size_t)bhc * 512 + e) * 256 + d] = f2bf(acc[i][j][r]);
            }
}

// ---------------------------------------------------------------------------
// Pass B: in-place diagonal scan on DtSt: read D, overwrite with entering S.
// ---------------------------------------------------------------------------
__global__ __launch_bounds__(256) void pass_b(unsigned short* __restrict__ DtSt,
                                              const float* __restrict__ gle) {
    const int gid = blockIdx.x * 256 + threadIdx.x;
    const int bh = gid >> 14;
    const int rem = gid & 16383;
    const int e = rem >> 5;
    const int d8 = (rem & 31) * 8;

    float S[8];
#pragma unroll
    for (int i = 0; i < 8; ++i) S[i] = 0.f;

    for (int n = 0; n < NCHUNK_; ++n) {
        const size_t row = (((size_t)(bh * 32 + n)) * 512 + e) * 256 + d8;
        us8 dv = *(const us8*)&DtSt[row];         // read D first
        us8 w;
#pragma unroll
        for (int i = 0; i < 8; ++i) w[i] = f2bf(S[i]);
        *(us8*)&DtSt[row] = w;                    // overwrite with entering S
        float4 e0 = *(const float4*)&gle[(size_t)(bh * 32 + n) * 256 + d8];
        float4 e1 = *(const float4*)&gle[(size_t)(bh * 32 + n) * 256 + d8 + 4];
        float E[8] = {e0.x, e0.y, e0.z, e0.w, e1.x, e1.y, e1.z, e1.w};
#pragma unroll
        for (int i = 0; i < 8; ++i) S[i] = (S[i] + bf2f(dv[i])) * E[i];
    }
}

// ---------------------------------------------------------------------------
// Pass C2: o[t][e] = [A_s | q_g][t][:] @ [v ; S^T][:][e]  (K=320), bf16 out.
// global_load_lds staging. grid(x=2 e-half, z=256 bhc).
// ---------------------------------------------------------------------------
__global__ __launch_bounds__(256) void pass_c2(const unsigned short* __restrict__ qg,
                                               const unsigned short* __restrict__ vT,
                                               const unsigned short* __restrict__ Asg,
                                               const unsigned short* __restrict__ St,
                                               unsigned short* __restrict__ o) {
    __shared__ __align__(16) unsigned short At[64 * 32];   // [t][k]
    __shared__ __align__(16) unsigned short Bt[256 * 32];  // [e][k]
    const int t = threadIdx.x;
    const int bhc = blockIdx.z;
    const int chunk = bhc & 31, bh = bhc >> 5;
    const int h = bh & 3, b = bh >> 2;
    const int s0 = chunk * 64;
    const int eh = blockIdx.x * 256;
    const int wave = t >> 6, lane = t & 63;
    const int quad = lane >> 4, l16 = lane & 15;
    const int we = wave * 64;

    f32x4 acc[4][4] = {};
    const int srow = t >> 2, scol = (t & 3) * 8;

    for (int kk0 = 0; kk0 < 10; ++kk0) {
        __syncthreads();
        if (kk0 < 2) {
            gload16(&Asg[(size_t)bhc * 4096 + srow * 64 + kk0 * 32 + scol],
                    &At[wave * 512]);
            const int t0 = kk0 * 32;
#pragma unroll
            for (int p = 0; p < 4; ++p) {
                int q = t + p * 256;
                int row = q >> 2, c8 = (q & 3) * 8;
                gload16(&vT[((size_t)bh * 512 + eh + row) * 2048 + s0 + t0 + c8],
                        &Bt[p * 2048 + wave * 512]);
            }
        } else {
            const int d0 = (kk0 - 2) * 32;
            gload16(&qg[((size_t)b * S_ + s0 + srow) * KD_ + h * DK_ + d0 + scol],
                    &At[wave * 512]);
#pragma unroll
            for (int p = 0; p < 4; ++p) {
                int q = t + p * 256;
                int row = q >> 2, c8 = (q & 3) * 8;
                gload16(&St[(((size_t)bhc) * 512 + eh + row) * 256 + d0 + c8],
                        &Bt[p * 2048 + wave * 512]);
            }
        }
        __syncthreads();

        bf16x8 af[4], bfr[4];
#pragma unroll
        for (int i = 0; i < 4; ++i)
            af[i] = *(const bf16x8*)&At[(i * 16 + l16) * 32 + quad * 8];
#pragma unroll
        for (int j = 0; j < 4; ++j)
            bfr[j] = *(const bf16x8*)&Bt[(we + j * 16 + l16) * 32 + quad * 8];
#pragma unroll
        for (int i = 0; i < 4; ++i)
#pragma unroll
            for (int j = 0; j < 4; ++j)
                acc[i][j] = __builtin_amdgcn_mfma_f32_16x16x32_bf16(af[i], bfr[j], acc[i][j], 0, 0, 0);
    }

#pragma unroll
    for (int i = 0; i < 4; ++i)
#pragma unroll
        for (int j = 0; j < 4; ++j)
#pragma unroll
            for (int r = 0; r < 4; ++r) {
                int m = i * 16 + quad * 4 + r;
                int e = eh + we + j * 16 + l16;
                o[((size_t)b * S_ + s0 + m) * VD_ + h * DV_ + e] = f2bf(acc[i][j][r]);
            }
}

// ---------------------------------------------------------------------------
// Post: RMS-norm over Dv=512 per (b,s,h) + gated swish; bf16 o in,
// g from fused qkvg cols (offset 4096, stride ND_), bf16 out.
// ---------------------------------------------------------------------------
__global__ __launch_bounds__(256) void postnorm(const unsigned short* __restrict__ o,
                                                const unsigned short* __restrict__ qkvg,
                                                const float* __restrict__ gnw,
                                                unsigned short* __restrict__ obf) {
    const int row = blockIdx.x;
    const int wave = threadIdx.x >> 6;
    const int lane = threadIdx.x & 63;
    const size_t base = (size_t)row * VD_ + wave * 512;
    const size_t gbase = (size_t)row * ND_ + 4096 + wave * 512;
    float x[8];
    float ss = 0.f;
#pragma unroll
    for (int j = 0; j < 8; ++j) {
        x[j] = bf2f(o[base + lane + j * 64]);
        ss += x[j] * x[j];
    }
#pragma unroll
    for (int off = 32; off; off >>= 1) ss += __shfl_xor(ss, off);
    const float inv = 1.0f / sqrtf(ss * (1.0f / 512.0f) + 1e-5f);
#pragma unroll
    for (int j = 0; j < 8; ++j) {
        int e = lane + j * 64;
        float gv = bf2f(qkvg[gbase + e]);
        float sig = 1.0f / (1.0f + expf(-gv));
        obf[base + e] = f2bf(x[j] * inv * gnw[e] * (gv * sig));
    }
}

// ---------------------------------------------------------------------------
extern "C" void kernel_launch(void* const* d_in, const int* in_sizes, int n_in,
                              void* d_out, int out_size, void* d_ws, size_t ws_size,
                              hipStream_t stream) {
    const float* x    = (const float*)d_in[0];
    const float* Wq   = (const float*)d_in[1];
    const float* Wk   = (const float*)d_in[2];
    const float* Wv   = (const float*)d_in[3];
    const float* Wgk1 = (const float*)d_in[4];
    const float* Wgk2 = (const float*)d_in[5];
    const float* bgk2 = (const float*)d_in[6];
    const float* Wg   = (const float*)d_in[7];
    const float* gnw  = (const float*)d_in[8];
    const float* Wo   = (const float*)d_in[9];
    float* out = (float*)d_out;

    float* ws = (float*)d_ws;
    const size_t MF = 1048576;
    typedef unsigned short us;
    // --- long-lived ---
    us* WotT   = (us*)(ws);                      // [2048][2048] bf16   0..2M
    us* qkvg   = (us*)(ws + 2 * MF);             // [4096][6144] bf16   2..15M (12.58M)
    us* qg     = (us*)(ws + 15 * MF);            // [4096][1024] bf16   15..17M
    us* kg     = (us*)(ws + 17 * MF);            // [4096][1024] bf16   17..19M
    us* kgT    = (us*)(ws + 19 * MF);            // [8*256][2048] bf16  19..21M
    us* vT     = (us*)(ws + 21 * MF);            // [8*512][2048] bf16  21..25M
    float* T   = ws + 25 * MF;                   // 65536
    float* gle = T + 65536;                      // 65536
    us* Asg    = (us*)(ws + 25 * MF + 131072);   // 1M shorts
    us* DtSt   = (us*)(ws + 25 * MF + 786432);   // 32M shorts: 25.75..41.75M
    // --- scratch (lifetime-shared) ---
    us* xb     = (us*)(ws + 41 * MF + 786432);   // x bf16 4M (dead after QKVG GEMM)
    float* gkb = ws + 41 * MF + 786432;          // gk fp32 4M (alias xb; after GEMM, dead after gate_prep)
    us* WcatT  = (us*)(ws + 45 * MF + 786432);   // [6144][2048] bf16 6.29M (dead after QKVG GEMM)
    us* o      = (us*)(ws + 45 * MF + 786432);   // o bf16 4M (alias WcatT; written by pass_c2)
    us* obf    = (us*)(ws + 49 * MF + 786432);   // normed o bf16 2M: 49.75..51.75M

    dim3 blk(256);
    conv_bf16<<<8192, blk, 0, stream>>>(x, xb);
    // concat W^T: rows [0..1024)=Wq, [1024..2048)=Wk, [2048..4096)=Wv, [4096..6144)=Wg
    tr_w<<<dim3(32, 64), blk, 0, stream>>>(Wq, WcatT,                   HD_, KD_);
    tr_w<<<dim3(32, 64), blk, 0, stream>>>(Wk, WcatT + 1024 * 2048,     HD_, KD_);
    tr_w<<<dim3(64, 64), blk, 0, stream>>>(Wv, WcatT + 2048 * 2048,     HD_, VD_);
    tr_w<<<dim3(64, 64), blk, 0, stream>>>(Wg, WcatT + (size_t)4096 * 2048, HD_, VD_);
    tr_w<<<dim3(64, 64), blk, 0, stream>>>(Wo, WotT, VD_, HD_);

    // fused projection: qkvg = xb @ WcatT^T  (M=4096, N=6144, K=2048)
    gemm_bt<<<dim3(48, 32), blk, 0, stream>>>(xb, WcatT, nullptr, qkvg, M_, ND_, HD_);
    tr_v<<<dim3(64, 128), blk, 0, stream>>>(qkvg, vT);

    gemm_n16<<<M_ / 16, blk, 0, stream>>>(x, Wgk1, T);
    gk_act<<<(M_ * KD_) / 256, blk, 0, stream>>>(T, Wgk2, bgk2, gkb);
    gate_prep<<<(B_ * H_ * NCHUNK_ * DK_) / 256, blk, 0, stream>>>(qkvg, gkb, qg, kg, kgT, gle);

    pass_c1<<<256, blk, 0, stream>>>(qg, kg, Asg);
    pass_a<<<dim3(2, 4, 256), blk, 0, stream>>>(kgT, vT, DtSt);
    pass_b<<<512, blk, 0, stream>>>(DtSt, gle);
    pass_c2<<<dim3(2, 1, 256), blk, 0, stream>>>(qg, vT, Asg, DtSt, o);
    postnorm<<<M_, blk, 0, stream>>>(o, qkvg, gnw, obf);
    gemm_bt<<<dim3(16, 32), blk, 0, stream>>>(obf, WotT, out, nullptr, M_, HD_, VD_);
}

// Round 3
// 487.133 us; speedup vs baseline: 1.1034x; 1.1034x over previous
//
#include <hip/hip_runtime.h>
#include <hip/hip_bf16.h>

// Problem constants
#define B_   2
#define S_   2048
#define HD_  2048
#define H_   4
#define DK_  256
#define DV_  512
#define KD_  1024   // H_*DK_
#define VD_  2048   // H_*DV_
#define ND_  6144   // fused N: q(1024) | k(1024) | v(2048) | g(2048)
#define M_   4096   // B_*S_
#define NCHUNK_ 32
#define CHUNK_  64

typedef __attribute__((ext_vector_type(8))) short bf16x8;
typedef __attribute__((ext_vector_type(4))) float f32x4;
typedef __attribute__((ext_vector_type(4))) unsigned short us4;
typedef __attribute__((ext_vector_type(8))) unsigned short us8;

__device__ __forceinline__ unsigned short f2bf(float f) {
    __hip_bfloat16 h = __float2bfloat16(f);
    return *reinterpret_cast<unsigned short*>(&h);
}
__device__ __forceinline__ float bf2f(unsigned short u) {
    unsigned int x = ((unsigned int)u) << 16;
    return *reinterpret_cast<float*>(&x);
}

// ---------------------------------------------------------------------------
// fp32 -> bf16 flat convert (x). One float4 per thread.
// ---------------------------------------------------------------------------
__global__ __launch_bounds__(256) void conv_bf16(const float* __restrict__ in,
                                                 unsigned short* __restrict__ out) {
    const int idx = blockIdx.x * 256 + threadIdx.x;
    float4 a = *(const float4*)&in[(size_t)idx * 4];
    us4 w; w.x = f2bf(a.x); w.y = f2bf(a.y); w.z = f2bf(a.z); w.w = f2bf(a.w);
    *(us4*)&out[(size_t)idx * 4] = w;
}

// ---------------------------------------------------------------------------
// Weight transpose: Wt[n][k](bf16) = W[k][n](fp32). 32x32 tiles via LDS.
// ---------------------------------------------------------------------------
__global__ __launch_bounds__(256) void tr_w(const float* __restrict__ W,
                                            unsigned short* __restrict__ Wt,
                                            int K, int N) {
    __shared__ float Ws[32][33];
    const int t = threadIdx.x;
    const int n0 = blockIdx.x * 32, k0 = blockIdx.y * 32;
    const int r = t >> 3, c4 = (t & 7) * 4;
    float4 a = *(const float4*)&W[(size_t)(k0 + r) * N + n0 + c4];
    Ws[r][c4 + 0] = a.x; Ws[r][c4 + 1] = a.y; Ws[r][c4 + 2] = a.z; Ws[r][c4 + 3] = a.w;
    __syncthreads();
    const int nr = t >> 3, kc4 = (t & 7) * 4;
    us4 w;
#pragma unroll
    for (int j = 0; j < 4; ++j) w[j] = f2bf(Ws[kc4 + j][nr]);
    *(us4*)&Wt[(size_t)(n0 + nr) * K + k0 + kc4] = w;
}

// ---------------------------------------------------------------------------
// v transpose: vT[((b*H+h)*512+e)*2048 + s] = qkvg[(b*2048+s)*6144 + 2048 + h*512 + e]
// bf16 in/out, 32x32 tiles. grid(x = 64 e-tiles, y = 128 s-tiles).
// ---------------------------------------------------------------------------
__global__ __launch_bounds__(256) void tr_v(const unsigned short* __restrict__ qkvg,
                                            unsigned short* __restrict__ vT) {
    __shared__ unsigned short Ws[32][36];
    const int t = threadIdx.x;
    const int c0 = blockIdx.x * 32;      // v-col within VD (0..2047)
    const int s0 = blockIdx.y * 32;      // global s (0..4095)
    {
        const int r = t >> 3, c4 = (t & 7) * 4;
        us4 w = *(const us4*)&qkvg[(size_t)(s0 + r) * ND_ + 2048 + c0 + c4];
        *(us4*)&Ws[r][c4] = w;
    }
    __syncthreads();
    const int er = t >> 3, sc4 = (t & 7) * 4;
    const int c = c0 + er;
    const int h = c >> 9, e = c & 511;
    const int b = s0 >> 11, srow = s0 & 2047;
    us4 w;
#pragma unroll
    for (int j = 0; j < 4; ++j) w[j] = Ws[sc4 + j][er];
    *(us4*)&vT[((size_t)(b * H_ + h) * 512 + e) * 2048 + srow + sc4] = w;
}

// ---------------------------------------------------------------------------
// bf16 GEMM: C[M][N] = A[M][K] @ Bt[N][K]^T. A,Bt bf16 row-major (K-contig).
// 128x128 tile, BK=64, register-prefetch pipelining (next tile's global loads
// issue before the MFMA block). XOR-swizzled LDS (short_off ^= (row&7)*8) on
// both write and read sides -> ~2-way bank access (free), fixes the 12.6M
// conflicts of the BK=32 linear layout at stride-64.
// ---------------------------------------------------------------------------
__global__ __launch_bounds__(256) void gemm_bt(const unsigned short* __restrict__ A,
                                               const unsigned short* __restrict__ Bt,
                                               float* __restrict__ Cf,
                                               unsigned short* __restrict__ Cb,
                                               int M, int N, int K) {
    __shared__ __align__(16) unsigned short As[128 * 64];
    __shared__ __align__(16) unsigned short Bs[128 * 64];
    const int t = threadIdx.x;
    const int m0 = blockIdx.y * 128, n0 = blockIdx.x * 128;
    const int wave = t >> 6, lane = t & 63;
    const int quad = lane >> 4, l16 = lane & 15;
    const int wm = (wave >> 1) * 64, wn = (wave & 1) * 64;

    f32x4 acc[4][4] = {};

    // staging: p=0..3, q=t+p*256: row=q>>3 (0..127), col=(q&7)*8 shorts.
    // 64 lanes of a wave cover 8 rows x 128B contiguous each.
    int aoff[4], boff[4], soff[4];
#pragma unroll
    for (int p = 0; p < 4; ++p) {
        int q = t + p * 256;
        int row = q >> 3, c = (q & 7) * 8;
        soff[p] = row * 64 + (c ^ ((row & 7) * 8));        // swizzled LDS dest
        aoff[p] = (m0 + row) * K + c;
        boff[p] = (n0 + row) * K + c;
    }

    us8 pa[4], pb[4];
#pragma unroll
    for (int p = 0; p < 4; ++p) {
        pa[p] = *(const us8*)&A[aoff[p]];
        pb[p] = *(const us8*)&Bt[boff[p]];
    }

    for (int k0 = 0; k0 < K; k0 += 64) {
        __syncthreads();
#pragma unroll
        for (int p = 0; p < 4; ++p) {
            *(us8*)&As[soff[p]] = pa[p];
            *(us8*)&Bs[soff[p]] = pb[p];
        }
        __syncthreads();
        if (k0 + 64 < K) {
#pragma unroll
            for (int p = 0; p < 4; ++p) {
                pa[p] = *(const us8*)&A[aoff[p] + k0 + 64];
                pb[p] = *(const us8*)&Bt[boff[p] + k0 + 64];
            }
        }

#pragma unroll
        for (int ks = 0; ks < 2; ++ks) {
            bf16x8 af[4], bfr[4];
#pragma unroll
            for (int i = 0; i < 4; ++i) {
                int r = wm + i * 16 + l16;
                af[i] = *(const bf16x8*)&As[r * 64 + ((ks * 32 + quad * 8) ^ ((r & 7) * 8))];
            }
#pragma unroll
            for (int j = 0; j < 4; ++j) {
                int r = wn + j * 16 + l16;
                bfr[j] = *(const bf16x8*)&Bs[r * 64 + ((ks * 32 + quad * 8) ^ ((r & 7) * 8))];
            }
#pragma unroll
            for (int i = 0; i < 4; ++i)
#pragma unroll
                for (int j = 0; j < 4; ++j)
                    acc[i][j] = __builtin_amdgcn_mfma_f32_16x16x32_bf16(af[i], bfr[j], acc[i][j], 0, 0, 0);
        }
    }

    if (Cb) {
#pragma unroll
        for (int i = 0; i < 4; ++i)
#pragma unroll
            for (int j = 0; j < 4; ++j)
#pragma unroll
                for (int r = 0; r < 4; ++r)
                    Cb[(size_t)(m0 + wm + i * 16 + quad * 4 + r) * N + n0 + wn + j * 16 + l16] = f2bf(acc[i][j][r]);
    } else {
#pragma unroll
        for (int i = 0; i < 4; ++i)
#pragma unroll
            for (int j = 0; j < 4; ++j)
#pragma unroll
                for (int r = 0; r < 4; ++r)
                    Cf[(size_t)(m0 + wm + i * 16 + quad * 4 + r) * N + n0 + wn + j * 16 + l16] = acc[i][j][r];
    }
}

// ---------------------------------------------------------------------------
// T = X @ Wgk1 (fp32, K=2048, N=16), LDS-staged.
// ---------------------------------------------------------------------------
__global__ __launch_bounds__(256) void gemm_n16(const float* __restrict__ X,
                                                const float* __restrict__ W,
                                                float* __restrict__ T) {
    __shared__ float Xs[16][129];
    __shared__ float Wsh[128][17];
    const int t = threadIdx.x;
    const int m0 = blockIdx.x * 16;
    const int mm = t >> 4, jj = t & 15;
    float acc = 0.f;
    for (int k0 = 0; k0 < HD_; k0 += 128) {
        __syncthreads();
#pragma unroll
        for (int p = 0; p < 2; ++p) {
            int q = t + p * 256;
            int r = q >> 5, c4 = (q & 31) * 4;
            float4 a = *(const float4*)&X[(size_t)(m0 + r) * HD_ + k0 + c4];
            Xs[r][c4 + 0] = a.x; Xs[r][c4 + 1] = a.y; Xs[r][c4 + 2] = a.z; Xs[r][c4 + 3] = a.w;
        }
#pragma unroll
        for (int p = 0; p < 8; ++p) {
            int q = t + p * 256;
            int r = q >> 4, c = q & 15;
            Wsh[r][c] = W[(size_t)(k0 + r) * 16 + c];
        }
        __syncthreads();
#pragma unroll 16
        for (int kk = 0; kk < 128; ++kk) acc += Xs[mm][kk] * Wsh[kk][jj];
    }
    T[(size_t)(m0 + mm) * 16 + jj] = acc;
}

// ---------------------------------------------------------------------------
// gk = log_sigmoid(T @ Wgk2 + bgk2) / 16.
// ---------------------------------------------------------------------------
__global__ __launch_bounds__(256) void gk_act(const float* __restrict__ T,
                                              const float* __restrict__ W2,
                                              const float* __restrict__ b2,
                                              float* __restrict__ gk) {
    const int idx = blockIdx.x * 256 + threadIdx.x;
    const int n = idx & 1023;
    const int m = idx >> 10;
    float acc = b2[n];
#pragma unroll
    for (int j = 0; j < 16; ++j) acc += T[m * 16 + j] * W2[j * 1024 + n];
    float ls = (acc < 0.f) ? (acc - log1pf(expf(acc))) : (-log1pf(expf(-acc)));
    gk[idx] = ls * 0.0625f;  // / GATE_NORMALIZER
}

// ---------------------------------------------------------------------------
// Gate prep: reads q,k columns of fused qkvg (stride ND_); writes
// qg,kg (compact t-major), kgT (d-major: [bh*256+d][s]), gle.
// ---------------------------------------------------------------------------
__global__ __launch_bounds__(256) void gate_prep(const unsigned short* __restrict__ qkvg,
                                                 const float* __restrict__ gk,
                                                 unsigned short* __restrict__ qg,
                                                 unsigned short* __restrict__ kg,
                                                 unsigned short* __restrict__ kgT,
                                                 float* __restrict__ glexp) {
    const int idx = blockIdx.x * 256 + threadIdx.x;
    const int d = idx & 255;
    const int chunk = (idx >> 8) & 31;
    const int h = (idx >> 13) & 3;
    const int b = idx >> 15;
    const int bh = b * H_ + h;
    const size_t col = h * 256 + d;
    const size_t rowbase = (size_t)b * S_ + chunk * 64;
    const size_t kgT_base = ((size_t)bh * 256 + d) * 2048 + chunk * 64;
    const float scale = 0.0625f;  // DK^-0.5
    float gc = 0.f;
    for (int t = 0; t < 64; ++t) {
        size_t r = rowbase + t;
        gc += gk[r * (size_t)KD_ + col];
        unsigned short qv = qkvg[r * (size_t)ND_ + col];
        unsigned short kv = qkvg[r * (size_t)ND_ + 1024 + col];
        unsigned short kgv = f2bf(bf2f(kv) * expf(-gc));
        qg[r * (size_t)KD_ + col] = f2bf(bf2f(qv) * expf(gc) * scale);
        kg[r * (size_t)KD_ + col] = kgv;
        kgT[kgT_base + t] = kgv;
    }
    glexp[idx] = expf(gc);
}

// ---------------------------------------------------------------------------
// Pass C1: A_s[bhc][t][j] = tril(q_g k_g^T) (64x64, K=256) -> bf16.
// Register-prefetch pipelined.
// ---------------------------------------------------------------------------
__global__ __launch_bounds__(256) void pass_c1(const unsigned short* __restrict__ qg,
                                               const unsigned short* __restrict__ kg,
                                               unsigned short* __restrict__ Asg) {
    __shared__ __align__(16) unsigned short Aq[64 * 32];
    __shared__ __align__(16) unsigned short Bk[64 * 32];
    const int t = threadIdx.x;
    const int bhc = blockIdx.x;
    const int chunk = bhc & 31, bh = bhc >> 5;
    const int h = bh & 3, b = bh >> 2;
    const int s0 = chunk * 64;
    const int wave = t >> 6, lane = t & 63;
    const int quad = lane >> 4, l16 = lane & 15;
    const int srow = t >> 2, scol = (t & 3) * 8;
    const size_t base = (size_t)b * S_ * KD_ + h * DK_ + (size_t)(s0 + srow) * KD_ + scol;

    f32x4 acc[4] = {};
    us8 aq = *(const us8*)&qg[base];
    us8 bk = *(const us8*)&kg[base];

    for (int k0 = 0; k0 < 256; k0 += 32) {
        __syncthreads();
        *(us8*)&Aq[srow * 32 + scol] = aq;
        *(us8*)&Bk[srow * 32 + scol] = bk;
        __syncthreads();
        if (k0 + 32 < 256) {
            aq = *(const us8*)&qg[base + k0 + 32];
            bk = *(const us8*)&kg[base + k0 + 32];
        }
        bf16x8 bfr = *(const bf16x8*)&Bk[(wave * 16 + l16) * 32 + quad * 8];
#pragma unroll
        for (int i = 0; i < 4; ++i) {
            bf16x8 af = *(const bf16x8*)&Aq[(i * 16 + l16) * 32 + quad * 8];
            acc[i] = __builtin_amdgcn_mfma_f32_16x16x32_bf16(af, bfr, acc[i], 0, 0, 0);
        }
    }

    const int j = wave * 16 + l16;
#pragma unroll
    for (int i = 0; i < 4; ++i)
#pragma unroll
        for (int r = 0; r < 4; ++r) {
            int m = i * 16 + quad * 4 + r;
            float val = (j <= m) ? acc[i][r] : 0.f;
            Asg[(size_t)bhc * 4096 + m * 64 + j] = f2bf(val);
        }
}

// ---------------------------------------------------------------------------
// Pass A: Dt[bhc][e][d] = sum_t v[t,e]*k_g[t,d]. A-rows from vT, B-rows from
// kgT — both contiguous us8 staging, conflict-free. grid(2,4,256).
// ---------------------------------------------------------------------------
__global__ __launch_bounds__(256) void pass_a(const unsigned short* __restrict__ kgT,
                                              const unsigned short* __restrict__ vT,
                                              unsigned short* __restrict__ Dt) {
    __shared__ __align__(16) unsigned short As[128 * 32];  // [e][t]
    __shared__ __align__(16) unsigned short Bs[128 * 32];  // [d][t]
    const int t = threadIdx.x;
    const int bhc = blockIdx.z;
    const int chunk = bhc & 31, bh = bhc >> 5;
    const int s0 = chunk * 64;
    const int e0 = blockIdx.y * 128;
    const int d0 = blockIdx.x * 128;
    const int wave = t >> 6, lane = t & 63;
    const int quad = lane >> 4, l16 = lane & 15;
    const int wm = (wave >> 1) * 64, wn = (wave & 1) * 64;

    f32x4 acc[4][4] = {};

    for (int k0 = 0; k0 < 64; k0 += 32) {
        __syncthreads();
#pragma unroll
        for (int p = 0; p < 2; ++p) {
            int q = t + p * 256;
            int row = q >> 2, c8 = (q & 3) * 8;
            us8 wv = *(const us8*)&vT[((size_t)bh * 512 + e0 + row) * 2048 + s0 + k0 + c8];
            *(us8*)&As[row * 32 + c8] = wv;
            us8 wk = *(const us8*)&kgT[((size_t)bh * 256 + d0 + row) * 2048 + s0 + k0 + c8];
            *(us8*)&Bs[row * 32 + c8] = wk;
        }
        __syncthreads();

        bf16x8 af[4], bfr[4];
#pragma unroll
        for (int i = 0; i < 4; ++i)
            af[i] = *(const bf16x8*)&As[(wm + i * 16 + l16) * 32 + quad * 8];
#pragma unroll
        for (int j = 0; j < 4; ++j)
            bfr[j] = *(const bf16x8*)&Bs[(wn + j * 16 + l16) * 32 + quad * 8];
#pragma unroll
        for (int i = 0; i < 4; ++i)
#pragma unroll
            for (int j = 0; j < 4; ++j)
                acc[i][j] = __builtin_amdgcn_mfma_f32_16x16x32_bf16(af[i], bfr[j], acc[i][j], 0, 0, 0);
    }

#pragma unroll
    for (int i = 0; i < 4; ++i)
#pragma unroll
        for (int j = 0; j < 4; ++j)
#pragma unroll
            for (int r = 0; r < 4; ++r) {
                size_t e = e0 + wm + i * 16 + quad * 4 + r;
                size_t d = d0 + wn + j * 16 + l16;
                Dt[((size_t)bhc * 512 + e) * 256 + d] = f2bf(acc[i][j][r]);
            }
}

// ---------------------------------------------------------------------------
// Pass B: in-place diagonal scan on DtSt: read D, overwrite with entering S.
// ---------------------------------------------------------------------------
__global__ __launch_bounds__(256) void pass_b(unsigned short* __restrict__ DtSt,
                                              const float* __restrict__ gle) {
    const int gid = blockIdx.x * 256 + threadIdx.x;
    const int bh = gid >> 14;
    const int rem = gid & 16383;
    const int e = rem >> 5;
    const int d8 = (rem & 31) * 8;

    float S[8];
#pragma unroll
    for (int i = 0; i < 8; ++i) S[i] = 0.f;

    for (int n = 0; n < NCHUNK_; ++n) {
        const size_t row = (((size_t)(bh * 32 + n)) * 512 + e) * 256 + d8;
        us8 dv = *(const us8*)&DtSt[row];         // read D first
        us8 w;
#pragma unroll
        for (int i = 0; i < 8; ++i) w[i] = f2bf(S[i]);
        *(us8*)&DtSt[row] = w;                    // overwrite with entering S
        float4 e0 = *(const float4*)&gle[(size_t)(bh * 32 + n) * 256 + d8];
        float4 e1 = *(const float4*)&gle[(size_t)(bh * 32 + n) * 256 + d8 + 4];
        float E[8] = {e0.x, e0.y, e0.z, e0.w, e1.x, e1.y, e1.z, e1.w};
#pragma unroll
        for (int i = 0; i < 8; ++i) S[i] = (S[i] + bf2f(dv[i])) * E[i];
    }
}

// ---------------------------------------------------------------------------
// Pass C2: o[t][e] = [A_s | q_g][t][:] @ [v ; S^T][:][e]  (K=320), bf16 out.
// v-staging from vT (contiguous rows). grid(x=2 e-half, z=256 bhc).
// ---------------------------------------------------------------------------
__global__ __launch_bounds__(256) void pass_c2(const unsigned short* __restrict__ qg,
                                               const unsigned short* __restrict__ vT,
                                               const unsigned short* __restrict__ Asg,
                                               const unsigned short* __restrict__ St,
                                               unsigned short* __restrict__ o) {
    __shared__ __align__(16) unsigned short At[64 * 32];   // [t][k]
    __shared__ __align__(16) unsigned short Bt[256 * 32];  // [e][k]
    const int t = threadIdx.x;
    const int bhc = blockIdx.z;
    const int chunk = bhc & 31, bh = bhc >> 5;
    const int h = bh & 3, b = bh >> 2;
    const int s0 = chunk * 64;
    const int eh = blockIdx.x * 256;
    const int wave = t >> 6, lane = t & 63;
    const int quad = lane >> 4, l16 = lane & 15;
    const int we = wave * 64;

    f32x4 acc[4][4] = {};

    for (int kk0 = 0; kk0 < 10; ++kk0) {
        __syncthreads();
        if (kk0 < 2) {
            {
                int row = t >> 2, c8 = (t & 3) * 8;
                us8 w = *(const us8*)&Asg[(size_t)bhc * 4096 + row * 64 + kk0 * 32 + c8];
                *(us8*)&At[row * 32 + c8] = w;
            }
            const int t0 = kk0 * 32;
#pragma unroll
            for (int p = 0; p < 4; ++p) {
                int q = t + p * 256;
                int row = q >> 2, c8 = (q & 3) * 8;
                us8 w = *(const us8*)&vT[((size_t)bh * 512 + eh + row) * 2048 + s0 + t0 + c8];
                *(us8*)&Bt[row * 32 + c8] = w;
            }
        } else {
            const int d0 = (kk0 - 2) * 32;
            {
                int row = t >> 2, c8 = (t & 3) * 8;
                us8 w = *(const us8*)&qg[((size_t)b * S_ + s0 + row) * KD_ + h * DK_ + d0 + c8];
                *(us8*)&At[row * 32 + c8] = w;
            }
#pragma unroll
            for (int p = 0; p < 4; ++p) {
                int q = t + p * 256;
                int row = q >> 2, c8 = (q & 3) * 8;
                us8 w = *(const us8*)&St[(((size_t)bhc) * 512 + eh + row) * 256 + d0 + c8];
                *(us8*)&Bt[row * 32 + c8] = w;
            }
        }
        __syncthreads();

        bf16x8 af[4], bfr[4];
#pragma unroll
        for (int i = 0; i < 4; ++i)
            af[i] = *(const bf16x8*)&At[(i * 16 + l16) * 32 + quad * 8];
#pragma unroll
        for (int j = 0; j < 4; ++j)
            bfr[j] = *(const bf16x8*)&Bt[(we + j * 16 + l16) * 32 + quad * 8];
#pragma unroll
        for (int i = 0; i < 4; ++i)
#pragma unroll
            for (int j = 0; j < 4; ++j)
                acc[i][j] = __builtin_amdgcn_mfma_f32_16x16x32_bf16(af[i], bfr[j], acc[i][j], 0, 0, 0);
    }

#pragma unroll
    for (int i = 0; i < 4; ++i)
#pragma unroll
        for (int j = 0; j < 4; ++j)
#pragma unroll
            for (int r = 0; r < 4; ++r) {
                int m = i * 16 + quad * 4 + r;
                int e = eh + we + j * 16 + l16;
                o[((size_t)b * S_ + s0 + m) * VD_ + h * DV_ + e] = f2bf(acc[i][j][r]);
            }
}

// ---------------------------------------------------------------------------
// Post: RMS-norm over Dv=512 per (b,s,h) + gated swish; bf16 o in,
// g from fused qkvg cols (offset 4096, stride ND_), bf16 out.
// ---------------------------------------------------------------------------
__global__ __launch_bounds__(256) void postnorm(const unsigned short* __restrict__ o,
                                                const unsigned short* __restrict__ qkvg,
                                                const float* __restrict__ gnw,
                                                unsigned short* __restrict__ obf) {
    const int row = blockIdx.x;
    const int wave = threadIdx.x >> 6;
    const int lane = threadIdx.x & 63;
    const size_t base = (size_t)row * VD_ + wave * 512;
    const size_t gbase = (size_t)row * ND_ + 4096 + wave * 512;
    float x[8];
    float ss = 0.f;
#pragma unroll
    for (int j = 0; j < 8; ++j) {
        x[j] = bf2f(o[base + lane + j * 64]);
        ss += x[j] * x[j];
    }
#pragma unroll
    for (int off = 32; off; off >>= 1) ss += __shfl_xor(ss, off);
    const float inv = 1.0f / sqrtf(ss * (1.0f / 512.0f) + 1e-5f);
#pragma unroll
    for (int j = 0; j < 8; ++j) {
        int e = lane + j * 64;
        float gv = bf2f(qkvg[gbase + e]);
        float sig = 1.0f / (1.0f + expf(-gv));
        obf[base + e] = f2bf(x[j] * inv * gnw[e] * (gv * sig));
    }
}

// ---------------------------------------------------------------------------
extern "C" void kernel_launch(void* const* d_in, const int* in_sizes, int n_in,
                              void* d_out, int out_size, void* d_ws, size_t ws_size,
                              hipStream_t stream) {
    const float* x    = (const float*)d_in[0];
    const float* Wq   = (const float*)d_in[1];
    const float* Wk   = (const float*)d_in[2];
    const float* Wv   = (const float*)d_in[3];
    const float* Wgk1 = (const float*)d_in[4];
    const float* Wgk2 = (const float*)d_in[5];
    const float* bgk2 = (const float*)d_in[6];
    const float* Wg   = (const float*)d_in[7];
    const float* gnw  = (const float*)d_in[8];
    const float* Wo   = (const float*)d_in[9];
    float* out = (float*)d_out;

    float* ws = (float*)d_ws;
    const size_t MF = 1048576;
    typedef unsigned short us;
    // --- long-lived ---
    us* WotT   = (us*)(ws);                      // [2048][2048] bf16   0..2M
    us* qkvg   = (us*)(ws + 2 * MF);             // [4096][6144] bf16   2..15M (12.58M)
    us* qg     = (us*)(ws + 15 * MF);            // [4096][1024] bf16   15..17M
    us* kg     = (us*)(ws + 17 * MF);            // [4096][1024] bf16   17..19M
    us* kgT    = (us*)(ws + 19 * MF);            // [8*256][2048] bf16  19..21M
    us* vT     = (us*)(ws + 21 * MF);            // [8*512][2048] bf16  21..25M
    float* T   = ws + 25 * MF;                   // 65536
    float* gle = T + 65536;                      // 65536
    us* Asg    = (us*)(ws + 25 * MF + 131072);   // 1M shorts
    us* DtSt   = (us*)(ws + 25 * MF + 786432);   // 32M shorts: 25.75..41.75M
    // --- scratch (lifetime-shared) ---
    us* xb     = (us*)(ws + 41 * MF + 786432);   // x bf16 4M (dead after QKVG GEMM)
    float* gkb = ws + 41 * MF + 786432;          // gk fp32 4M (alias xb; after GEMM, dead after gate_prep)
    us* WcatT  = (us*)(ws + 45 * MF + 786432);   // [6144][2048] bf16 6.29M (dead after QKVG GEMM)
    us* o      = (us*)(ws + 45 * MF + 786432);   // o bf16 4M (alias WcatT; written by pass_c2)
    us* obf    = (us*)(ws + 49 * MF + 786432);   // normed o bf16 2M: 49.75..51.75M

    dim3 blk(256);
    conv_bf16<<<8192, blk, 0, stream>>>(x, xb);
    // concat W^T: rows [0..1024)=Wq, [1024..2048)=Wk, [2048..4096)=Wv, [4096..6144)=Wg
    tr_w<<<dim3(32, 64), blk, 0, stream>>>(Wq, WcatT,                   HD_, KD_);
    tr_w<<<dim3(32, 64), blk, 0, stream>>>(Wk, WcatT + 1024 * 2048,     HD_, KD_);
    tr_w<<<dim3(64, 64), blk, 0, stream>>>(Wv, WcatT + 2048 * 2048,     HD_, VD_);
    tr_w<<<dim3(64, 64), blk, 0, stream>>>(Wg, WcatT + (size_t)4096 * 2048, HD_, VD_);
    tr_w<<<dim3(64, 64), blk, 0, stream>>>(Wo, WotT, VD_, HD_);

    // fused projection: qkvg = xb @ WcatT^T  (M=4096, N=6144, K=2048)
    gemm_bt<<<dim3(48, 32), blk, 0, stream>>>(xb, WcatT, nullptr, qkvg, M_, ND_, HD_);
    tr_v<<<dim3(64, 128), blk, 0, stream>>>(qkvg, vT);

    gemm_n16<<<M_ / 16, blk, 0, stream>>>(x, Wgk1, T);
    gk_act<<<(M_ * KD_) / 256, blk, 0, stream>>>(T, Wgk2, bgk2, gkb);
    gate_prep<<<(B_ * H_ * NCHUNK_ * DK_) / 256, blk, 0, stream>>>(qkvg, gkb, qg, kg, kgT, gle);

    pass_c1<<<256, blk, 0, stream>>>(qg, kg, Asg);
    pass_a<<<dim3(2, 4, 256), blk, 0, stream>>>(kgT, vT, DtSt);
    pass_b<<<512, blk, 0, stream>>>(DtSt, gle);
    pass_c2<<<dim3(2, 1, 256), blk, 0, stream>>>(qg, vT, Asg, DtSt, o);
    postnorm<<<M_, blk, 0, stream>>>(o, qkvg, gnw, obf);
    gemm_bt<<<dim3(16, 32), blk, 0, stream>>>(obf, WotT, out, nullptr, M_, HD_, VD_);
}